// Round 11
// baseline (187.734 us; speedup 1.0000x reference)
//
#include <hip/hip_runtime.h>
#include <stdint.h>

// y[b,o,w] = relu(bias[o] + sum_{i,kh} W[o,i,kh] * x[b,i,kh,w])
// q=i&3 split: q<2 ("rep") -> pre-sum W over tt => K=512; q>=2 ("pos") keeps
// the gathered K=8192. r23: faithful m201 8-phase port on r16's VERIFIED math
// (r16 passed refcheck; its failure was the sync skeleton). 256x256 tile,
// 8 waves, BK=64, 4 phases/K-tile, per phase:
//   {ds_reads -> issue ONE stage-unit -> s_barrier -> setprio(1) 16 MFMA
//    setprio(0) -> counted vmcnt -> s_barrier}
// Unit issue order u0,u2,u1,u3 (A-h0, B-k0, A-h1, B-k1) == consumption order
// -> every unit has a 3-4 phase flight window. Steady-state waits: vmcnt(4)
// at end of P0/P1/P3 (none at P2); tail tile vmcnt(2)/vmcnt(0). Own-vmcnt ->
// s_barrier aggregation (m201-verified). m=XCD colocation kept (FETCH-
// verified 17MB -> all staging L2-resident). grid 256 = 4m x 8n x 8z.
// 3 dispatches: prep -> gemm -> finalize.

#define NDIM 1024
#define TK   16
#define KPOS 8192    // pos K: 512 i's * 16 kh
#define KREP 512     // rep K: 32 (nl,q) * 16 kh
#define NCOL 2048    // 64 batches * 32 width

typedef unsigned short u16;
typedef uint32_t u32;
typedef u16   u16x8  __attribute__((ext_vector_type(8)));
typedef __bf16 bf16x8 __attribute__((ext_vector_type(8)));
typedef float  f32x4  __attribute__((ext_vector_type(4)));

__device__ __forceinline__ u16 f2bf(float x) {
    union { float f; unsigned u; } v; v.f = x;
    unsigned r = 0x7FFFu + ((v.u >> 16) & 1u);   // round-to-nearest-even
    return (u16)((v.u + r) >> 16);
}

// async global->LDS, 16B/lane; LDS dest is wave-uniform base + lane*16
__device__ __forceinline__ void load_lds_16B(const u16* g, u16* l) {
    __builtin_amdgcn_global_load_lds(
        (__attribute__((address_space(1))) void*)(uintptr_t)g,
        (__attribute__((address_space(3))) void*)(unsigned)(uintptr_t)l,
        16, 0, 0);
}

// ---------------------------------------------------------------------------
// Kernel 1 (fused, grid-partitioned):  [unchanged, verified]
// ---------------------------------------------------------------------------
#define PREP_TOPK 256
#define PREP_ZERO 512
#define PREP_W    1024
#define PREP_F1T  256

__global__ __launch_bounds__(256) void prep_kernel(const float* __restrict__ f1,
                                                   const float* __restrict__ W,
                                                   int* __restrict__ idx,
                                                   u16* __restrict__ Wb,
                                                   u16* __restrict__ W1b,
                                                   u16* __restrict__ f1t,
                                                   float* __restrict__ out) {
    const int bid = blockIdx.x;
    const int t = threadIdx.x;
    if (bid < PREP_TOPK) {
        // ---- top-16 ----
        const int lane = t & 63;
        const int row  = bid * 4 + (t >> 6);
        float v[16];
        const float* src = f1 + row * NDIM + lane;
        #pragma unroll
        for (int j = 0; j < 16; ++j) v[j] = src[j * 64];
        for (int sel = 0; sel < TK; ++sel) {
            float best = -3.402823466e38f; int bg = 0x7fffffff;
            #pragma unroll
            for (int j = 0; j < 16; ++j)
                if (v[j] > best) { best = v[j]; bg = j * 64 + lane; }
            #pragma unroll
            for (int s = 1; s < 64; s <<= 1) {
                float ov = __shfl_xor(best, s);
                int   og = __shfl_xor(bg, s);
                if (ov > best || (ov == best && og < bg)) { best = ov; bg = og; }
            }
            if (lane == sel) idx[row * TK + sel] = bg;
            #pragma unroll
            for (int j = 0; j < 16; ++j)
                if (bg == j * 64 + lane) v[j] = -3.402823466e38f;
        }
    } else if (bid < PREP_TOPK + PREP_ZERO) {
        // ---- zero the 8MB output accumulator ----
        const int zb = bid - PREP_TOPK;
        f32x4 z = {0.f, 0.f, 0.f, 0.f};
        float* p = out + (size_t)zb * 4096 + t * 16;
        #pragma unroll
        for (int j = 0; j < 4; ++j) *(f32x4*)(p + j * 4) = z;
    } else if (bid < PREP_TOPK + PREP_ZERO + PREP_W) {
        // ---- W-path: one block per output row o ----
        const int o = bid - PREP_TOPK - PREP_ZERO;   // 0..1023
        const float* wrow = W + (size_t)o * 16384;
        u16* wbrow = Wb + (size_t)o * KPOS;
        // pos half: contiguous permutation, coalesced read+write
        #pragma unroll
        for (int j = 0; j < 4; ++j) {
            const int v = j * 2048 + t * 8;              // pos-flat index
            const int u = ((v >> 5) << 6) + 32 + (v & 31);
            float4 a = *(const float4*)(wrow + u);
            float4 b = *(const float4*)(wrow + u + 4);
            u16x8 ov;
            ov[0] = f2bf(a.x); ov[1] = f2bf(a.y); ov[2] = f2bf(a.z); ov[3] = f2bf(a.w);
            ov[4] = f2bf(b.x); ov[5] = f2bf(b.y); ov[6] = f2bf(b.z); ov[7] = f2bf(b.w);
            *(u16x8*)(wbrow + v) = ov;
        }
        // rep half: reduce over tt
        #pragma unroll
        for (int h = 0; h < 2; ++h) {
            const int kr = h * 256 + t;        // 0..511
            const int nl = kr >> 5, e = kr & 31;
            const float* base = wrow + nl * 1024 + e;
            float s = 0.f;
            #pragma unroll
            for (int tt = 0; tt < 16; ++tt) s += base[tt * 64];
            W1b[o * KREP + kr] = f2bf(s);
        }
    } else {
        // ---- f1 -> f1t bf16 transpose (w-major, kh half-swapped by w>>2&1) ----
        const int gb = bid - PREP_TOPK - PREP_ZERO - PREP_W;   // 0..255
        const int unit = t >> 5;               // 0..7
        const int w = t & 31;
        const int rq = gb * 8 + unit;          // 0..2047
        const int row = rq >> 1, q = rq & 1;
        const float* src = f1 + row * NDIM + q * 512;
        const int swp = ((w >> 2) & 1) * 8;
        u16 tmp[16];
        #pragma unroll
        for (int kh = 0; kh < 16; ++kh)
            tmp[kh ^ swp] = f2bf(src[kh * 32 + w]);   // coalesced per-kh across lanes
        u16* dst = f1t + ((size_t)row * 2 + q) * 512 + w * 16;
        *(u16x8*)(dst)     = *(u16x8*)(tmp);
        *(u16x8*)(dst + 8) = *(u16x8*)(tmp + 8);
    }
}

// ---------------------------------------------------------------------------
// Kernel 2: bf16 MFMA GEMM, 256x256 tile, BK=64, 256 blocks (1/CU):
//   xcd = f&7 -> (m = xcd>>1, zl = xcd&1); g = f>>3 -> (n = g&7, zh = g>>3);
//   z = zh*2+zl.  17 K-tiles/block: 16 pos + 1 rep. All index/staging/
//   fragment/epilogue math = r16 (refcheck-passed). NEW: m201 sync skeleton.
// Stage units (2 x load_lds_16B/thread each):
//   u0 = A rows [0,128), u1 = A rows [128,256), u2 = B ci{0,1}, u3 = B ci{2,3}
// Phase p of tile t:   (issue order u0,u2,u1,u3 == consumption order)
//   P0: read bfr(ks0)+af(h0,ks0); issue u0(t+1); BAR; MFMA h0; vmcnt(4); BAR
//   P1: read af(h1,ks0);          issue u2(t+1); BAR; MFMA h1; vmcnt(4); BAR
//   P2: read bfr(ks1)+af(h0,ks1); issue u1(t+1); BAR; MFMA h0;           BAR
//   P3: read af(h1,ks1);          issue u3(t+1); BAR; MFMA h1; vmcnt(4); BAR
// Each wait confirms the unit needed next phase (issued 3-4 phases ago,
// L2-resident via colocation); 4 loads (=2 units) stay in flight across
// every barrier. Tail tile: vmcnt(2) @P0, vmcnt(0) @P1.
// ---------------------------------------------------------------------------
#define BM 256
#define BN 256
#define BK 64

__global__ __launch_bounds__(512, 2) void gemm_kernel(const u16* __restrict__ Ap,
                                                      const u16* __restrict__ A1,
                                                      const u16* __restrict__ f1t,
                                                      const int* __restrict__ idx,
                                                      float* __restrict__ out) {
    __shared__ __align__(16) u16 As[2][BM * BK];   // 2x32KB, [row][chunk^(row&7)]
    __shared__ __align__(16) u16 Bs[2][32 * 512];  // 2x32KB, [ci][bl][w][half]
    __shared__ __align__(8) int idxO[544];          // [uu 0..67][bl 0..7]

    const int f = blockIdx.x;            // 0..255
    const int xcd = f & 7;
    const int m  = xcd >> 1;             // 0..3
    const int zl = xcd & 1;
    const int g  = f >> 3;
    const int n  = g & 7;                // 0..7
    const int zh = g >> 3;               // 0..3
    const int z  = zh * 2 + zl;          // 0..7
    const int t    = threadIdx.x;
    const int lane = t & 63;
    const int wave = t >> 6;             // 0..7
    const int wm   = (wave >> 2) * 128;  // M-half of this wave
    const int wn   = (wave & 3) * 64;    // N-quarter of this wave
    const int quad = lane >> 4;
    const int l16  = lane & 15;
    const int sw   = l16 & 7;            // A-read chunk XOR key
    const int qh   = quad & 1;
    const int o0 = m * BM;
    const int n0 = n * BN;
    const int nb0 = n * 8;               // first batch of this tile

    // build idxO (verified r16/r13): entry uu*8+bl
    {
        const int uu = t >> 3, bl = t & 7;
        const int ip = z * 64 + uu;                      // global pos k16-unit
        const int nl = ip >> 5, tt = (ip >> 1) & 15, q = ip & 1;
        const int row = idx[((nb0 + bl) * 16 + nl) * TK + tt];
        idxO[t] = ((row << 1) + q) << 9;                 // u16-element offset
        if (t < 32) {
            const int uur = t >> 3, bl2 = t & 7;
            const int ur = z * 4 + uur;                  // global rep unit
            const int rrow = (nb0 + bl2) * 16 + (ur >> 1);
            idxO[512 + t] = ((rrow << 1) + (ur & 1)) << 9;
        }
    }

    f32x4 acc[8][4] = {};

    // A staging (verified r16): thread t covers LDS 16B-slot of each half;
    // row = h*128 + (t>>3), c8 = t&7; source chunk = c8^(row&7)
    const int r0 = t >> 3;
    const int c0 = t & 7;
    const int csw = (c0 ^ (r0 & 7)) * 8;

    auto stageA = [&](int tt1, int h, int nb) {
        u16* dst = &As[nb][h * 8192 + wave * 512];
        if (tt1 < 16) {
            const u16* s0 = Ap + (size_t)(o0 + h * 128 + r0) * KPOS
                               + z * 1024 + tt1 * 64 + csw;
            load_lds_16B(s0, dst);
            load_lds_16B(s0 + (size_t)64 * KPOS, dst + 4096);
        } else {
            const u16* s0 = A1 + (size_t)(o0 + h * 128 + r0) * KREP
                               + z * 64 + csw;
            load_lds_16B(s0, dst);
            load_lds_16B(s0 + (size_t)64 * KREP, dst + 4096);
        }
    };

    // B staging (verified r16): wave w stages rows (ci = kk*2+j, bl = w)
    auto stageB = [&](int tt1, int kk, int nb) {
        #pragma unroll
        for (int j = 0; j < 2; ++j) {
            const int ci = kk * 2 + j;
            const int uu = (tt1 < 16) ? (tt1 * 4 + ci) : (64 + ci);
            const int off = idxO[uu * 8 + wave];
            load_lds_16B(f1t + off + lane * 8,
                         &Bs[nb][(ci * 8 + wave) * 512]);
        }
    };

#define LOAD_A(MH, KS)                                                        \
    {                                                                         \
        _Pragma("unroll")                                                     \
        for (int mt = 0; mt < 4; ++mt) {                                      \
            const int row = wm + (MH) * 64 + mt * 16 + l16;                   \
            u16x8 bits = *(const u16x8*)(Acur + row * 64                      \
                                         + ((((KS) * 4 + quad) ^ sw) * 8));   \
            af[mt] = __builtin_bit_cast(bf16x8, bits);                        \
        }                                                                     \
    }

#define LOAD_B(KS)                                                            \
    {                                                                         \
        const int ci = (KS) * 2 + (quad >> 1);                                \
        _Pragma("unroll")                                                     \
        for (int nt = 0; nt < 4; ++nt) {                                      \
            const int nn = wn + nt * 16 + l16;                                \
            const int bl = nn >> 5, w = nn & 31;                              \
            u16x8 bits = *(const u16x8*)(Bcur + (ci * 8 + bl) * 512 + w * 16  \
                                         + ((qh ^ ((w >> 2) & 1)) * 8));      \
            bfr[nt] = __builtin_bit_cast(bf16x8, bits);                       \
        }                                                                     \
    }

#define MFMA_BLK(MH)                                                          \
    {                                                                         \
        __builtin_amdgcn_s_setprio(1);                                        \
        _Pragma("unroll")                                                     \
        for (int mt = 0; mt < 4; ++mt)                                        \
            _Pragma("unroll")                                                 \
            for (int nt = 0; nt < 4; ++nt)                                    \
                acc[(MH) * 4 + mt][nt] = __builtin_amdgcn_mfma_f32_16x16x32_bf16( \
                    af[mt], bfr[nt], acc[(MH) * 4 + mt][nt], 0, 0, 0);        \
        __builtin_amdgcn_s_setprio(0);                                        \
    }

    // prologue: idxO visible, stage tile 0 fully, drain once
    __syncthreads();
    stageA(0, 0, 0); stageB(0, 0, 0); stageA(0, 1, 0); stageB(0, 1, 0);
    asm volatile("s_waitcnt vmcnt(0)" ::: "memory");
    __builtin_amdgcn_s_barrier();

    for (int tk = 0; tk < 17; ++tk) {
        const int cur = tk & 1, nxt = cur ^ 1;
        const int tn = tk + 1;
        const bool pre = (tn <= 16);
        const u16* Acur = As[cur];
        const u16* Bcur = Bs[cur];
        bf16x8 af[4], bfr[4];

        // ---- P0: consume u0,u2(t); issue u0(t+1) ----
        LOAD_B(0)
        LOAD_A(0, 0)
        if (pre) stageA(tn, 0, nxt);
        __builtin_amdgcn_s_barrier();
        MFMA_BLK(0)
        if (tk < 16) { asm volatile("s_waitcnt vmcnt(4)" ::: "memory"); }
        else         { asm volatile("s_waitcnt vmcnt(2)" ::: "memory"); }
        __builtin_amdgcn_s_barrier();

        // ---- P1: consume u1(t); issue u2(t+1) ----
        LOAD_A(1, 0)
        if (pre) stageB(tn, 0, nxt);
        __builtin_amdgcn_s_barrier();
        MFMA_BLK(1)
        if (tk < 16) { asm volatile("s_waitcnt vmcnt(4)" ::: "memory"); }
        else         { asm volatile("s_waitcnt vmcnt(0)" ::: "memory"); }
        __builtin_amdgcn_s_barrier();

        // ---- P2: consume u3(t); issue u1(t+1) ----
        LOAD_B(1)
        LOAD_A(0, 1)
        if (pre) stageA(tn, 1, nxt);
        __builtin_amdgcn_s_barrier();
        MFMA_BLK(0)
        __builtin_amdgcn_s_barrier();

        // ---- P3: issue u3(t+1) ----
        LOAD_A(1, 1)
        if (pre) stageB(tn, 1, nxt);
        __builtin_amdgcn_s_barrier();
        MFMA_BLK(1)
        if (tk < 16) { asm volatile("s_waitcnt vmcnt(4)" ::: "memory"); }
        __builtin_amdgcn_s_barrier();
    }

    // epilogue (verified r16): C/D row=quad*4+reg, col=l16; atomic scatter
    #pragma unroll
    for (int nt = 0; nt < 4; ++nt) {
        const int nn = n0 + wn + nt * 16 + l16;
        const int bb = nn >> 5, w = nn & 31;
        #pragma unroll
        for (int mi = 0; mi < 8; ++mi) {
            #pragma unroll
            for (int r = 0; r < 4; ++r) {
                const int o = o0 + wm + mi * 16 + quad * 4 + r;
                unsafeAtomicAdd(out + (size_t)(bb * 16 + (o >> 6)) * 2048
                                    + (o & 63) * 32 + w,
                                acc[mi][nt][r]);
            }
        }
    }
#undef LOAD_A
#undef LOAD_B
#undef MFMA_BLK
}

// ---------------------------------------------------------------------------
// Kernel 3: in-place bias + relu on the accumulated output.
// ---------------------------------------------------------------------------
__global__ __launch_bounds__(256) void finalize_kernel(float* __restrict__ out,
                                                       const float* __restrict__ bias) {
    const int tid = blockIdx.x * 256 + threadIdx.x;
    const int f = tid * 4;
    const int o = ((f >> 11) & 15) * 64 + ((f & 2047) >> 5);
    const float bv = bias[o];
    float4 x = *(float4*)(out + f);
    x.x = fmaxf(x.x + bv, 0.f);
    x.y = fmaxf(x.y + bv, 0.f);
    x.z = fmaxf(x.z + bv, 0.f);
    x.w = fmaxf(x.w + bv, 0.f);
    *(float4*)(out + f) = x;
}

// ---------------------------------------------------------------------------
extern "C" void kernel_launch(void* const* d_in, const int* in_sizes, int n_in,
                              void* d_out, int out_size, void* d_ws, size_t ws_size,
                              hipStream_t stream) {
    const float* f1   = (const float*)d_in[0];   // [1024][1024]
    const float* Wc   = (const float*)d_in[1];   // [1024][1024][16][1]
    const float* bias = (const float*)d_in[2];   // [1024]
    float* out = (float*)d_out;                  // [1024][2048]

    // workspace layout (bytes):
    //   idx:  0         (64KB)
    //   Wb:   65536     (1024*8192*2 = 16MB)
    //   W1b:  16842752  (1024*512*2  = 1MB)
    //   f1t:  17891328  (1024*2*512*2 = 2MB)
    int* idx = (int*)d_ws;
    u16* Wb  = (u16*)((char*)d_ws + 65536);
    u16* W1b = (u16*)((char*)d_ws + 16842752);
    u16* f1t = (u16*)((char*)d_ws + 17891328);

    prep_kernel<<<PREP_TOPK + PREP_ZERO + PREP_W + PREP_F1T,
                  256, 0, stream>>>(f1, Wc, idx, Wb, W1b, f1t, out);
    gemm_kernel<<<256, 512, 0, stream>>>(Wb, W1b, f1t, idx, out);
    finalize_kernel<<<(NDIM * NCOL) / (4 * 256), 256, 0, stream>>>(out, bias);
}